// Round 8
// baseline (743.848 us; speedup 1.0000x reference)
//
#include <hip/hip_runtime.h>
#include <math.h>

#define XDIM 47764
#define HDIM 128
#define LDIM 8
#define VTDIM 3620
#define WDIM 32
#define RDIM 8
#define NDIM 512
#define RW 256            // W*R
#define DDIM 48276        // X + RW + 2H
#define FIXED 48148       // X + RW + H (rows of si independent of h_prev_layer)
#define ETDIM 395
#define EPSV 1e-8f

#define CHUNK 768
#define NCHUNK 63         // ceil(48148/768)
#define K1_COMPUTE (32 * NCHUNK)   // 2016
#define K1_COPYB 128
#define K1_TOTAL (K1_COMPUTE + K1_COPYB)   // 2144
#define K45_TOTAL 235
#define K7_TOTAL 256

// ws layout (float offsets)
#define OFF_PARTIAL 0          // 32*63*128 = 258048
#define OFF_FIXED   258048     // 32*128 (unused now, kept for spacing)
#define OFF_WREC    262144     // 32*128*128 = 524288
#define OFF_FLAT    786432     // 1024
#define OFF_ERAW    787456     // 512
#define OFF_WW      787968     // 512
#define OFF_MEMNEW  788480     // 16384
#define OFF_CR      804864     // 4096
#define OFF_RM      808960     // 32
#define OFF_FW      808992     // 4096
#define OFF_BW      813088     // 4096
#define OFF_RV      817184     // 256
#define OFF_CNT     817440     // 3 uint counters (memset 0 each launch)

typedef float f4 __attribute__((ext_vector_type(4)));

__device__ __forceinline__ f4 ntload4(const float* p) {
    return __builtin_nontemporal_load((const f4*)p);
}

__device__ inline float sigm(float x) { return 1.f / (1.f + expf(-x)); }
__device__ inline float log_sigmoid(float x) {
    return (x >= 0.f) ? -log1pf(expf(-x)) : (x - log1pf(expf(x)));
}

// returns true for exactly the LAST block of the grid to reach this point
__device__ __forceinline__ bool elect_last(unsigned* cnt, unsigned total) {
    __shared__ unsigned e;
    __threadfence();                       // release: make our writes visible
    if (threadIdx.x == 0) e = atomicAdd(cnt, 1u);
    __syncthreads();
    if (e != total - 1) return false;
    __threadfence();                       // acquire: see everyone's writes
    return true;
}

// ---- K1: gate pre-activations (nontemporal) + wrec compaction
//      elected last block: partial-reduce + bias + 8-layer LSTM chain
__global__ __launch_bounds__(256) void k1_partial(
    const float* __restrict__ x_in, const float* __restrict__ lrv,
    const float* __restrict__ hprev,
    const float* __restrict__ Wi, const float* __restrict__ Wf,
    const float* __restrict__ Wo, const float* __restrict__ Ws,
    const float* __restrict__ bi, const float* __restrict__ bf,
    const float* __restrict__ bo, const float* __restrict__ bs,
    const float* __restrict__ old_st, float* __restrict__ ws)
{
    const int bid = blockIdx.x;
    const int t   = threadIdx.x;

    if (bid >= K1_COMPUTE) {
        // compaction: W*[l][FIXED+j][h] -> wrec[combo][j][h]
        int cb = bid - K1_COMPUTE;
        #pragma unroll
        for (int r = 0; r < 4; ++r) {
            int idx4  = cb * 1024 + r * 256 + t;
            int flat  = idx4 << 2;
            int combo = flat >> 14;
            int rem   = flat & 16383;
            int j = rem >> 7, h = rem & 127;
            int g = combo >> 3, l = combo & 7;
            const float* Wg = (g == 0) ? Wi : (g == 1) ? Wf : (g == 2) ? Wo : Ws;
            float4 v = *reinterpret_cast<const float4*>(
                Wg + ((size_t)l * DDIM + FIXED + j) * HDIM + h);
            *reinterpret_cast<float4*>(ws + OFF_WREC + flat) = v;
        }
    } else {
        const int combo = bid / NCHUNK;
        const int chunk = bid % NCHUNK;
        const int g = combo >> 3, l = combo & 7;
        const float* __restrict__ Wg = (g == 0) ? Wi : (g == 1) ? Wf : (g == 2) ? Wo : Ws;
        const int d0 = chunk * CHUNK;

        __shared__ float s_lds[CHUNK];
        for (int i = t; i < CHUNK; i += 256) {
            int d = d0 + i;
            float v = 0.f;
            if (d < XDIM)            v = x_in[d];
            else if (d < XDIM + RW)  v = lrv[d - XDIM];
            else if (d < FIXED)      v = hprev[l * HDIM + (d - XDIM - RW)];
            s_lds[i] = v;
        }
        __syncthreads();

        const int c4 = t & 15;
        const int p  = t >> 4;
        const int r0 = p * 48;
        const float* wp = Wg + ((size_t)l * DDIM + d0 + r0) * HDIM + (c4 << 2);

        f4 a = {0.f, 0.f, 0.f, 0.f};
        f4 b = {0.f, 0.f, 0.f, 0.f};

        if (chunk != NCHUNK - 1) {
            #pragma unroll 4
            for (int i = 0; i < 48; ++i) {
                float s = s_lds[r0 + i];
                const f4 w0 = ntload4(wp);
                const f4 w1 = ntload4(wp + 64);
                wp += HDIM;
                a += s * w0;
                b += s * w1;
            }
        } else {
            for (int i = 0; i < 48; ++i) {
                if (d0 + r0 + i >= FIXED) break;
                float s = s_lds[r0 + i];
                const f4 w0 = ntload4(wp);
                const f4 w1 = ntload4(wp + 64);
                wp += HDIM;
                a += s * w0;
                b += s * w1;
            }
        }

        __shared__ f4 red[16][32];
        red[p][c4]      = a;
        red[p][c4 + 16] = b;
        __syncthreads();
        if (t < 32) {
            f4 s = red[0][t];
            #pragma unroll
            for (int q = 1; q < 16; ++q) s += red[q][t];
            *reinterpret_cast<f4*>(ws + OFF_PARTIAL +
                ((size_t)(combo * NCHUNK + chunk)) * HDIM + (t << 2)) = s;
        }
    }

    // ---- election: last block runs partial-reduce + LSTM chain
    if (!elect_last((unsigned*)(ws + OFF_CNT), K1_TOTAL)) return;

    const int g = t >> 7;        // 0/1; thread also handles gate g+2
    const int h = t & 127;

    // reduce 63 chunk-partials + bias for combos (g*8+l) and ((g+2)*8+l)
    float fx0[LDIM], fx1[LDIM];
    const float* bg0 = (g == 0) ? bi : bf;
    const float* bg1 = (g == 0) ? bo : bs;
    #pragma unroll
    for (int l = 0; l < LDIM; ++l) {
        int c0 = (g * 8 + l) * NCHUNK, c1 = ((g + 2) * 8 + l) * NCHUNK;
        float a0 = bg0[l * HDIM + h], a1 = bg1[l * HDIM + h];
        for (int c = 0; c < NCHUNK; ++c) {
            a0 += ws[OFF_PARTIAL + (size_t)(c0 + c) * HDIM + h];
            a1 += ws[OFF_PARTIAL + (size_t)(c1 + c) * HDIM + h];
        }
        fx0[l] = a0; fx1[l] = a1;
    }

    __shared__ float hp[128];
    __shared__ float gl[4][128];
    if (t < 128) hp[t] = 0.f;
    __syncthreads();

    for (int l = 0; l < LDIM; ++l) {
        const float* w0 = ws + OFF_WREC + (size_t)(g * 8 + l) * 16384 + h;
        const float* w1 = ws + OFF_WREC + (size_t)((g + 2) * 8 + l) * 16384 + h;
        float a0 = fx0[l], a1 = fx1[l];
        #pragma unroll 8
        for (int j = 0; j < 128; ++j) {
            float hj = hp[j];
            a0 += hj * w0[j * 128];
            a1 += hj * w1[j * 128];
        }
        gl[g][h] = a0;
        gl[g + 2][h] = a1;
        __syncthreads();
        if (t < 128) {
            float ig = sigm(gl[0][t]);
            float fg = sigm(gl[1][t]);
            float og = sigm(gl[2][t]);
            float ss = tanhf(gl[3][t]);
            float st = fg * old_st[l * HDIM + t] + ig * ss;
            float hn = og * tanhf(st);
            hp[t] = hn;
            ws[OFF_FLAT + l * HDIM + t] = hn;
        }
        __syncthreads();
    }
}

// ---- K45: flat@Wy -> out (blocks 0..226), flat@We -> eraw (227..234)
//      elected last block: full DNC small-math (usage/alloc/write/memory/cr)
__global__ __launch_bounds__(512) void k45_out_E(
    const float* __restrict__ Wy, const float* __restrict__ We,
    const float* __restrict__ memory, const float* __restrict__ lrw,
    const float* __restrict__ lu, const float* __restrict__ lww,
    float* __restrict__ dout, float* __restrict__ ws)
{
    const int blk = blockIdx.x, t = threadIdx.x;
    const int lane = t & 63, wid = t >> 6;
    __shared__ float smem[2048];

    if (blk < 227) {
        float* flat_s = smem;          // 1024
        float* pr     = smem + 1024;   // 512
        flat_s[t]       = ws[OFF_FLAT + t];
        flat_s[512 + t] = ws[OFF_FLAT + 512 + t];
        __syncthreads();
        const int ks = t >> 4, v16 = t & 15;
        const int v = blk * 16 + v16;
        float acc = 0.f;
        if (v < VTDIM) {
            const float* Wp = Wy + (size_t)(ks * 32) * VTDIM + v;
            #pragma unroll 8
            for (int k = 0; k < 32; ++k)
                acc += flat_s[ks * 32 + k] * Wp[(size_t)k * VTDIM];
        }
        pr[ks * 16 + v16] = acc;
        __syncthreads();
        if (t < 16) {
            float s = 0.f;
            #pragma unroll
            for (int q = 0; q < 32; ++q) s += pr[q * 16 + t];
            int vv = blk * 16 + t;
            if (vv < VTDIM) dout[vv] = s;
        }
    } else {
        float* flat_s = smem;
        float* pr     = smem + 1024;
        flat_s[t]       = ws[OFF_FLAT + t];
        flat_s[512 + t] = ws[OFF_FLAT + 512 + t];
        __syncthreads();
        const int ks = t >> 6, e64 = t & 63;
        const int e = (blk - 227) * 64 + e64;
        float acc = 0.f;
        if (e < ETDIM) {
            const float* Wp = We + (size_t)(ks * 128) * ETDIM + e;
            #pragma unroll 8
            for (int k = 0; k < 128; ++k)
                acc += flat_s[ks * 128 + k] * Wp[(size_t)k * ETDIM];
        }
        pr[ks * 64 + e64] = acc;
        __syncthreads();
        if (t < 64) {
            float s = 0.f;
            #pragma unroll
            for (int q = 0; q < 8; ++q) s += pr[q * 64 + t];
            int ee = (blk - 227) * 64 + t;
            if (ee < ETDIM) ws[OFF_ERAW + ee] = s;
        }
    }

    if (!elect_last((unsigned*)(ws + OFF_CNT) + 1, K45_TOTAL)) return;

    // ===== DNC small-math (512 threads) =====
    __shared__ float Es[416], rk[256], wk[32], er[32], wvv[32];
    __shared__ float fgs[8], rss[8], rm[24], scal[4], u_s[512];
    __shared__ float wred[8], wred8[64], srk[8];

    if (t < ETDIM) Es[t] = ws[OFF_ERAW + t];
    __syncthreads();

    if (t < 256)                 rk[t] = Es[t];
    if (t >= 256 && t < 264)     rss[t - 256] = 1.f - log_sigmoid(Es[t]);
    if (t >= 264 && t < 296)     wk[t - 264] = Es[t];
    if (t == 296)                scal[0] = 1.f - log_sigmoid(Es[296]);
    if (t >= 297 && t < 329)     er[t - 297] = sigm(Es[t]);
    if (t >= 329 && t < 361)     wvv[t - 329] = Es[t];
    if (t >= 361 && t < 369)     fgs[t - 361] = sigm(Es[t]);
    if (t == 369)                scal[1] = sigm(Es[369]);
    if (t == 370)                scal[2] = sigm(Es[370]);
    if (t >= 384 && t < 392) {
        int r = t - 384;
        float a = Es[371 + 3*r], b = Es[372 + 3*r], c = Es[373 + 3*r];
        float mx = fmaxf(a, fmaxf(b, c));
        float ea = expf(a - mx), eb = expf(b - mx), ec = expf(c - mx);
        float s = ea + eb + ec;
        rm[3*r] = ea / s; rm[3*r + 1] = eb / s; rm[3*r + 2] = ec / s;
    }
    __syncthreads();

    float psi = 1.f;
    #pragma unroll
    for (int r = 0; r < 8; ++r) psi *= 1.f - fgs[r] * lrw[t * 8 + r];
    float ua = lu[t], ub = lww[t];
    float u_t = (ua + ub - ua * ub) * psi;
    u_s[t] = u_t;
    __syncthreads();

    float prod = 1.f;
    for (int j = 0; j < 512; ++j) {
        float uj = u_s[j];
        bool before = (uj < u_t) || (uj == u_t && j < t);
        prod *= before ? uj : 1.f;
    }
    float alloc_t = (1.f - u_t) * prod;

    float s2 = 0.f;
    #pragma unroll
    for (int w = 0; w < 32; ++w) s2 += wk[w] * wk[w];
    float wkinv = 1.f / fmaxf(sqrtf(s2), EPSV);

    float mrow[32];
    float dotv = 0.f, nn = 0.f;
    #pragma unroll
    for (int w = 0; w < 32; ++w) {
        float m = memory[t * 32 + w];
        mrow[w] = m; dotv += m * wk[w]; nn += m * m;
    }
    float score = scal[0] * wkinv * dotv / fmaxf(sqrtf(nn), EPSV);
    float v = score;
    #pragma unroll
    for (int o = 32; o > 0; o >>= 1) v = fmaxf(v, __shfl_xor(v, o));
    if (lane == 0) wred[wid] = v;
    __syncthreads();
    float mx = wred[0];
    #pragma unroll
    for (int qq = 1; qq < 8; ++qq) mx = fmaxf(mx, wred[qq]);
    __syncthreads();
    float e = expf(score - mx);
    v = e;
    #pragma unroll
    for (int o = 32; o > 0; o >>= 1) v += __shfl_xor(v, o);
    if (lane == 0) wred[wid] = v;
    __syncthreads();
    float ssum = 0.f;
    #pragma unroll
    for (int qq = 0; qq < 8; ++qq) ssum += wred[qq];
    float cwv = e / ssum;

    float wwn = scal[2] * (scal[1] * alloc_t + (1.f - scal[1]) * cwv);
    ws[OFF_WW + t] = wwn;

    float nn2 = 0.f;
    #pragma unroll
    for (int w = 0; w < 32; ++w) {
        float mn = mrow[w] * (1.f - wwn * er[w]) + wwn * wvv[w];
        mrow[w] = mn; nn2 += mn * mn;
        ws[OFF_MEMNEW + t * 32 + w] = mn;
    }
    float inv2 = 1.f / fmaxf(sqrtf(nn2), EPSV);

    if (t < 8) {
        float s3 = 0.f;
        #pragma unroll
        for (int w = 0; w < 32; ++w) { float x = rk[w * 8 + t]; s3 += x * x; }
        srk[t] = rss[t] / fmaxf(sqrtf(s3), EPSV);
    }
    __syncthreads();

    float sc[8];
    #pragma unroll
    for (int r = 0; r < 8; ++r) {
        float d2 = 0.f;
        #pragma unroll
        for (int w = 0; w < 32; ++w) d2 += mrow[w] * rk[w * 8 + r];
        sc[r] = srk[r] * inv2 * d2;
    }
    #pragma unroll
    for (int r = 0; r < 8; ++r) {
        float x = sc[r];
        #pragma unroll
        for (int o = 32; o > 0; o >>= 1) x = fmaxf(x, __shfl_xor(x, o));
        if (lane == 0) wred8[wid * 8 + r] = x;
    }
    __syncthreads();
    float mxr[8];
    #pragma unroll
    for (int r = 0; r < 8; ++r) {
        float m = wred8[r];
        #pragma unroll
        for (int qq = 1; qq < 8; ++qq) m = fmaxf(m, wred8[qq * 8 + r]);
        mxr[r] = m;
    }
    __syncthreads();
    float ex[8];
    #pragma unroll
    for (int r = 0; r < 8; ++r) {
        ex[r] = expf(sc[r] - mxr[r]);
        float x = ex[r];
        #pragma unroll
        for (int o = 32; o > 0; o >>= 1) x += __shfl_xor(x, o);
        if (lane == 0) wred8[wid * 8 + r] = x;
    }
    __syncthreads();
    #pragma unroll
    for (int r = 0; r < 8; ++r) {
        float sm = 0.f;
        #pragma unroll
        for (int qq = 0; qq < 8; ++qq) sm += wred8[qq * 8 + r];
        ws[OFF_CR + t * 8 + r] = ex[r] / sm;
    }
    if (t < 24) ws[OFF_RM + t] = rm[t];
}

// ---- K7: linkage fw/bw (2 fw rows + 2 bw rows per block)
//      elected last block: rw -> rv
__global__ __launch_bounds__(512) void k7_linkage(
    const float* __restrict__ linkage, const float* __restrict__ prec,
    const float* __restrict__ lrw, float* __restrict__ ws)
{
    const int blk = blockIdx.x, t = threadIdx.x;
    const int lane = t & 63, wid = t >> 6;
    __shared__ float smem[6272];

    {
        float* lrw_s  = smem;          // 512*9 = 4608 (padded)
        float* ww_s   = smem + 4608;   // 512
        float* rowred = smem + 5120;   // 64
        for (int i = t; i < 4096; i += 512)
            lrw_s[(i >> 3) * 9 + (i & 7)] = lrw[i];
        ww_s[t] = ws[OFF_WW + t];
        __syncthreads();

        const float pt = prec[t];
        const float wwt = ww_s[t];
        float la[8];
        #pragma unroll
        for (int r = 0; r < 8; ++r) la[r] = lrw_s[t * 9 + r];

        #pragma unroll
        for (int pass = 0; pass < 4; ++pass) {
            const int i = blk * 2 + (pass & 1);
            float lm;
            if (pass < 2) {   // fw: Lm[i][t]
                float lj = linkage[(size_t)i * 512 + t];
                lm = (t == i) ? 0.f : (1.f - ww_s[i] - wwt) * lj + ww_s[i] * pt;
            } else {          // bw: Lm[t][i]
                float lj = linkage[(size_t)t * 512 + i];
                lm = (t == i) ? 0.f : (1.f - wwt - ww_s[i]) * lj + wwt * prec[i];
            }
            #pragma unroll
            for (int r = 0; r < 8; ++r) {
                float v = lm * la[r];
                #pragma unroll
                for (int o = 32; o > 0; o >>= 1) v += __shfl_xor(v, o);
                if (lane == 0) rowred[wid * 8 + r] = v;
            }
            __syncthreads();
            if (t < 8) {
                float s = 0.f;
                #pragma unroll
                for (int w = 0; w < 8; ++w) s += rowred[w * 8 + t];
                ws[((pass < 2) ? OFF_FW : OFF_BW) + i * 8 + t] = s;
            }
            __syncthreads();
        }
    }

    if (!elect_last((unsigned*)(ws + OFF_CNT) + 2, K7_TOTAL)) return;
    __syncthreads();

    // ===== rw -> rv =====
    float* rw_s = smem;          // 4096
    float* rred = smem + 4096;   // 2048
    __shared__ float rm_s[24];
    if (t < 24) rm_s[t] = ws[OFF_RM + t];
    __syncthreads();
    for (int idx = t; idx < 4096; idx += 512) {
        int r = idx & 7;
        rw_s[idx] = ws[OFF_BW + idx] * rm_s[r * 3]
                  + ws[OFF_CR + idx] * rm_s[r * 3 + 1]
                  + ws[OFF_FW + idx] * rm_s[r * 3 + 2];
    }
    __syncthreads();

    const int g = t >> 5, w = t & 31;    // 16 groups x 32 n each
    float acc[8] = {0,0,0,0,0,0,0,0};
    for (int n = g * 32; n < g * 32 + 32; ++n) {
        float m = ws[OFF_MEMNEW + n * 32 + w];
        #pragma unroll
        for (int r = 0; r < 8; ++r) acc[r] += m * rw_s[n * 8 + r];
    }
    #pragma unroll
    for (int r = 0; r < 8; ++r) {
        float v = acc[r] + __shfl_xor(acc[r], 32);
        if (lane < 32) rred[(wid * 32 + w) * 8 + r] = v;
    }
    __syncthreads();
    if (t < 256) {
        int w2 = t >> 3, r2 = t & 7;
        float s = 0.f;
        #pragma unroll
        for (int qq = 0; qq < 8; ++qq) s += rred[(qq * 32 + w2) * 8 + r2];
        ws[OFF_RV + w2 * 8 + r2] = s;
    }
}

// ---- K8b: out += rv @ Wr (60 blocks: 4 kc x 15 vt)
__global__ __launch_bounds__(256) void k8b_wr(
    const float* __restrict__ Wr, float* __restrict__ dout,
    const float* __restrict__ ws)
{
    const int blk = blockIdx.x, t = threadIdx.x;
    const int vt = blk % 15, kc = blk / 15;
    __shared__ float rv_s[64];
    if (t < 64) rv_s[t] = ws[OFF_RV + kc * 64 + t];
    __syncthreads();
    int v = vt * 256 + t;
    if (v < VTDIM) {
        float acc = 0.f;
        const float* Wp = Wr + (size_t)kc * 64 * VTDIM + v;
        #pragma unroll 8
        for (int k = 0; k < 64; ++k) acc += rv_s[k] * Wp[(size_t)k * VTDIM];
        atomicAdd(&dout[v], acc);
    }
}

extern "C" void kernel_launch(void* const* d_in, const int* in_sizes, int n_in,
                              void* d_out, int out_size, void* d_ws, size_t ws_size,
                              hipStream_t stream)
{
    const float* x_in   = (const float*)d_in[0];
    const float* Wi     = (const float*)d_in[1];
    const float* bi     = (const float*)d_in[2];
    const float* Wf     = (const float*)d_in[3];
    const float* bf     = (const float*)d_in[4];
    const float* Wo     = (const float*)d_in[5];
    const float* bo     = (const float*)d_in[6];
    const float* Wss    = (const float*)d_in[7];
    const float* bs     = (const float*)d_in[8];
    const float* Wy     = (const float*)d_in[9];
    const float* We     = (const float*)d_in[10];
    const float* Wr     = (const float*)d_in[11];
    const float* memory = (const float*)d_in[12];
    const float* lrv    = (const float*)d_in[13];
    const float* hprev  = (const float*)d_in[14];
    const float* old_st = (const float*)d_in[15];
    const float* prec   = (const float*)d_in[16];
    const float* linkage= (const float*)d_in[17];
    const float* lrw    = (const float*)d_in[18];
    const float* lu     = (const float*)d_in[19];
    const float* lww    = (const float*)d_in[20];
    float* out = (float*)d_out;
    float* ws  = (float*)d_ws;

    hipMemsetAsync((void*)(ws + OFF_CNT), 0, 3 * sizeof(unsigned), stream);

    k1_partial<<<K1_TOTAL, 256, 0, stream>>>(
        x_in, lrv, hprev, Wi, Wf, Wo, Wss, bi, bf, bo, bs, old_st, ws);
    k45_out_E<<<K45_TOTAL, 512, 0, stream>>>(Wy, We, memory, lrw, lu, lww, out, ws);
    k7_linkage<<<K7_TOTAL, 512, 0, stream>>>(linkage, prec, lrw, ws);
    k8b_wr<<<60, 256, 0, stream>>>(Wr, out, ws);
}

// Round 10
// 240.644 us; speedup vs baseline: 3.0911x; 3.0911x over previous
//
#include <hip/hip_runtime.h>
#include <math.h>

#define XDIM 47764
#define HDIM 128
#define LDIM 8
#define VTDIM 3620
#define WDIM 32
#define RDIM 8
#define NDIM 512
#define RW 256            // W*R
#define DDIM 48276        // X + RW + 2H
#define FIXED 48148       // X + RW + H (rows of si independent of h_prev_layer)
#define ETDIM 395
#define EPSV 1e-8f

#define CHUNK 768
#define NCHUNK 63         // ceil(48148/768)
#define K1_COMPUTE (32 * NCHUNK)   // 2016
#define K1_COPYB 128
#define KE_BLOCKS 8

// ws layout (float offsets)
#define OFF_FIXED   0          // 32*128 gate preacts (atomic accum, memset 0)
#define OFF_CNT     4096       // 1 uint counter (memset 0)
#define OFF_WREC    262144     // bf16! 32*128*128 ushorts = 1 MB
#define OFF_FLAT    786432     // 1024
#define OFF_ERAW    787456     // 512
#define OFF_WW      787968     // 512
#define OFF_MEMNEW  788480     // 16384
#define OFF_CR      804864     // 4096
#define OFF_RM      808960     // 32
#define OFF_FW      808992     // 4096
#define OFF_BW      813088     // 4096
#define OFF_RV      817184     // 256

typedef float f4 __attribute__((ext_vector_type(4)));
typedef unsigned short us4 __attribute__((ext_vector_type(4)));

__device__ __forceinline__ f4 ntload4(const float* p) {
    return __builtin_nontemporal_load((const f4*)p);
}
__device__ __forceinline__ unsigned short f2bf(float f) {   // RNE
    unsigned u = __float_as_uint(f);
    return (unsigned short)((u + 0x7FFFu + ((u >> 16) & 1u)) >> 16);
}
__device__ __forceinline__ float bf2f(unsigned short b) {
    return __uint_as_float(((unsigned)b) << 16);
}

__device__ inline float sigm(float x) { return 1.f / (1.f + expf(-x)); }
__device__ inline float log_sigmoid(float x) {
    return (x >= 0.f) ? -log1pf(expf(-x)) : (x - log1pf(expf(x)));
}

// last-block election — small grids only (device fences are costly at scale).
// RACE-FIX (R9 post-mortem): __syncthreads() BEFORE the release fence+atomic,
// so all of this block's global stores happen-before tid0's counter bump
// (canonical threadFenceReduction pattern, multi-writer generalization).
__device__ __forceinline__ bool elect_last(unsigned* cnt, unsigned total) {
    __shared__ unsigned e;
    __syncthreads();                       // all block stores program-complete
    __threadfence();                       // cumulative device-scope release
    if (threadIdx.x == 0) e = atomicAdd(cnt, 1u);
    __syncthreads();
    if (e != total - 1) return false;
    __threadfence();                       // acquire: see all writers' stores
    return true;
}

// ---- K1: gate pre-activations (nontemporal, atomic into fixed)
//      + wrec compaction to bf16
__global__ __launch_bounds__(256) void k1_partial(
    const float* __restrict__ x_in, const float* __restrict__ lrv,
    const float* __restrict__ hprev,
    const float* __restrict__ Wi, const float* __restrict__ Wf,
    const float* __restrict__ Wo, const float* __restrict__ Ws,
    float* __restrict__ ws)
{
    const int bid = blockIdx.x;
    const int t   = threadIdx.x;

    if (bid >= K1_COMPUTE) {
        // compaction: W*[l][FIXED+j][h] -> wrec_bf16[combo][j][h]
        int cb = bid - K1_COMPUTE;
        unsigned short* wrec = (unsigned short*)(ws + OFF_WREC);
        #pragma unroll
        for (int r = 0; r < 4; ++r) {
            int idx4  = cb * 1024 + r * 256 + t;
            int flat  = idx4 << 2;
            int combo = flat >> 14;
            int rem   = flat & 16383;
            int j = rem >> 7, h = rem & 127;
            int g = combo >> 3, l = combo & 7;
            const float* Wg = (g == 0) ? Wi : (g == 1) ? Wf : (g == 2) ? Wo : Ws;
            float4 v = *reinterpret_cast<const float4*>(
                Wg + ((size_t)l * DDIM + FIXED + j) * HDIM + h);
            us4 o = { f2bf(v.x), f2bf(v.y), f2bf(v.z), f2bf(v.w) };
            *reinterpret_cast<us4*>(wrec + flat) = o;
        }
        return;
    }

    const int combo = bid / NCHUNK;
    const int chunk = bid % NCHUNK;
    const int g = combo >> 3, l = combo & 7;
    const float* __restrict__ Wg = (g == 0) ? Wi : (g == 1) ? Wf : (g == 2) ? Wo : Ws;
    const int d0 = chunk * CHUNK;

    __shared__ float s_lds[CHUNK];
    for (int i = t; i < CHUNK; i += 256) {
        int d = d0 + i;
        float v = 0.f;
        if (d < XDIM)            v = x_in[d];
        else if (d < XDIM + RW)  v = lrv[d - XDIM];
        else if (d < FIXED)      v = hprev[l * HDIM + (d - XDIM - RW)];
        s_lds[i] = v;
    }
    __syncthreads();

    const int c4 = t & 15;
    const int p  = t >> 4;
    const int r0 = p * 48;
    const float* wp = Wg + ((size_t)l * DDIM + d0 + r0) * HDIM + (c4 << 2);

    f4 a = {0.f, 0.f, 0.f, 0.f};
    f4 b = {0.f, 0.f, 0.f, 0.f};

    if (chunk != NCHUNK - 1) {
        #pragma unroll 4
        for (int i = 0; i < 48; ++i) {
            float s = s_lds[r0 + i];
            const f4 w0 = ntload4(wp);
            const f4 w1 = ntload4(wp + 64);
            wp += HDIM;
            a += s * w0;
            b += s * w1;
        }
    } else {
        for (int i = 0; i < 48; ++i) {
            if (d0 + r0 + i >= FIXED) break;
            float s = s_lds[r0 + i];
            const f4 w0 = ntload4(wp);
            const f4 w1 = ntload4(wp + 64);
            wp += HDIM;
            a += s * w0;
            b += s * w1;
        }
    }

    __shared__ f4 red[16][32];
    red[p][c4]      = a;
    red[p][c4 + 16] = b;
    __syncthreads();
    if (t < 32) {
        f4 s = red[0][t];
        #pragma unroll
        for (int q = 1; q < 16; ++q) s += red[q][t];
        float* fx = ws + OFF_FIXED + combo * HDIM + (t << 2);
        atomicAdd(fx + 0, s.x);
        atomicAdd(fx + 1, s.y);
        atomicAdd(fx + 2, s.z);
        atomicAdd(fx + 3, s.w);
    }
}

// ---- K3: bias + 8-layer LSTM chain (1 block, 1024 thr, bf16 weights) ------
__global__ __launch_bounds__(1024) void k3_recurrent(
    const float* __restrict__ bi, const float* __restrict__ bf,
    const float* __restrict__ bo, const float* __restrict__ bs,
    const float* __restrict__ old_st, float* __restrict__ ws)
{
    const int t = threadIdx.x;          // 0..1023
    const int g = t >> 8;               // gate 0..3
    const int q = (t >> 7) & 1;         // half of j-dim
    const int h = t & 127;
    const unsigned short* wrec = (const unsigned short*)(ws + OFF_WREC);

    __shared__ float hp[128];
    __shared__ float gl[4][2][128];

    float fx[LDIM];
    const float* bg = (g == 0) ? bi : (g == 1) ? bf : (g == 2) ? bo : bs;
    if (q == 0) {
        #pragma unroll
        for (int l = 0; l < LDIM; ++l)
            fx[l] = ws[OFF_FIXED + (g * 8 + l) * HDIM + h] + bg[l * HDIM + h];
    }
    if (t < 128) hp[t] = 0.f;
    __syncthreads();

    for (int l = 0; l < LDIM; ++l) {
        int combo = g * 8 + l;
        float acc = (q == 0) ? fx[l] : 0.f;
        const unsigned short* wr = wrec + (size_t)combo * 16384 + (q << 6) * 128 + h;
        #pragma unroll 8
        for (int j = 0; j < 64; ++j)
            acc += hp[(q << 6) + j] * bf2f(wr[j * 128]);
        gl[g][q][h] = acc;
        __syncthreads();
        if (t < 128) {
            float ig = sigm(gl[0][0][t] + gl[0][1][t]);
            float fg = sigm(gl[1][0][t] + gl[1][1][t]);
            float og = sigm(gl[2][0][t] + gl[2][1][t]);
            float ss = tanhf(gl[3][0][t] + gl[3][1][t]);
            float st = fg * old_st[l * HDIM + t] + ig * ss;
            float hn = og * tanhf(st);
            hp[t] = hn;
            ws[OFF_FLAT + l * HDIM + t] = hn;
        }
        __syncthreads();
    }
}

// ---- KE6: flat@We -> E_raw (8 blocks, direct store); elected: DNC small-math
__global__ __launch_bounds__(512) void kE6(
    const float* __restrict__ We,
    const float* __restrict__ memory, const float* __restrict__ lrw,
    const float* __restrict__ lu, const float* __restrict__ lww,
    float* __restrict__ ws)
{
    const int blk = blockIdx.x, t = threadIdx.x;
    const int lane = t & 63, wid = t >> 6;

    {
        __shared__ float flat_s[1024];
        __shared__ float pr[512];
        flat_s[t]       = ws[OFF_FLAT + t];
        flat_s[512 + t] = ws[OFF_FLAT + 512 + t];
        __syncthreads();
        const int ks = t >> 6, e64 = t & 63;     // 8 k-segs of 128
        const int e = blk * 64 + e64;
        float acc = 0.f;
        if (e < ETDIM) {
            const float* Wp = We + (size_t)(ks * 128) * ETDIM + e;
            #pragma unroll 8
            for (int k = 0; k < 128; ++k)
                acc += flat_s[ks * 128 + k] * Wp[(size_t)k * ETDIM];
        }
        pr[ks * 64 + e64] = acc;
        __syncthreads();
        if (t < 64) {
            int ee = blk * 64 + t;
            if (ee < ETDIM) {
                float s = 0.f;
                #pragma unroll
                for (int qq = 0; qq < 8; ++qq) s += pr[qq * 64 + t];
                ws[OFF_ERAW + ee] = s;
            }
        }
    }

    if (!elect_last((unsigned*)(ws + OFF_CNT), KE_BLOCKS)) return;
    __syncthreads();

    // ===== DNC small-math (512 threads) =====
    __shared__ float Es[416], rk[256], wk[32], er[32], wvv[32];
    __shared__ float fgs[8], rss[8], rm[24], scal[4], u_s[512];
    __shared__ float wred[8], wred8[64], srk[8];

    if (t < ETDIM) Es[t] = ws[OFF_ERAW + t];
    if (t < 256) ws[OFF_RV + t] = 0.f;          // zero rv for k7 atomics
    __syncthreads();

    if (t < 256)                 rk[t] = Es[t];
    if (t >= 256 && t < 264)     rss[t - 256] = 1.f - log_sigmoid(Es[t]);
    if (t >= 264 && t < 296)     wk[t - 264] = Es[t];
    if (t == 296)                scal[0] = 1.f - log_sigmoid(Es[296]);
    if (t >= 297 && t < 329)     er[t - 297] = sigm(Es[t]);
    if (t >= 329 && t < 361)     wvv[t - 329] = Es[t];
    if (t >= 361 && t < 369)     fgs[t - 361] = sigm(Es[t]);
    if (t == 369)                scal[1] = sigm(Es[369]);
    if (t == 370)                scal[2] = sigm(Es[370]);
    if (t >= 384 && t < 392) {
        int r = t - 384;
        float a = Es[371 + 3*r], b = Es[372 + 3*r], c = Es[373 + 3*r];
        float mx = fmaxf(a, fmaxf(b, c));
        float ea = expf(a - mx), eb = expf(b - mx), ec = expf(c - mx);
        float s = ea + eb + ec;
        rm[3*r] = ea / s; rm[3*r + 1] = eb / s; rm[3*r + 2] = ec / s;
    }
    __syncthreads();

    float psi = 1.f;
    #pragma unroll
    for (int r = 0; r < 8; ++r) psi *= 1.f - fgs[r] * lrw[t * 8 + r];
    float ua = lu[t], ub = lww[t];
    float u_t = (ua + ub - ua * ub) * psi;
    u_s[t] = u_t;
    __syncthreads();

    float prod = 1.f;
    for (int j = 0; j < 512; ++j) {
        float uj = u_s[j];
        bool before = (uj < u_t) || (uj == u_t && j < t);
        prod *= before ? uj : 1.f;
    }
    float alloc_t = (1.f - u_t) * prod;

    float s2 = 0.f;
    #pragma unroll
    for (int w = 0; w < 32; ++w) s2 += wk[w] * wk[w];
    float wkinv = 1.f / fmaxf(sqrtf(s2), EPSV);

    float mrow[32];
    float dotv = 0.f, nn = 0.f;
    #pragma unroll
    for (int w = 0; w < 32; ++w) {
        float m = memory[t * 32 + w];
        mrow[w] = m; dotv += m * wk[w]; nn += m * m;
    }
    float score = scal[0] * wkinv * dotv / fmaxf(sqrtf(nn), EPSV);
    float v = score;
    #pragma unroll
    for (int o = 32; o > 0; o >>= 1) v = fmaxf(v, __shfl_xor(v, o));
    if (lane == 0) wred[wid] = v;
    __syncthreads();
    float mx = wred[0];
    #pragma unroll
    for (int qq = 1; qq < 8; ++qq) mx = fmaxf(mx, wred[qq]);
    __syncthreads();
    float e = expf(score - mx);
    v = e;
    #pragma unroll
    for (int o = 32; o > 0; o >>= 1) v += __shfl_xor(v, o);
    if (lane == 0) wred[wid] = v;
    __syncthreads();
    float ssum = 0.f;
    #pragma unroll
    for (int qq = 0; qq < 8; ++qq) ssum += wred[qq];
    float cwv = e / ssum;

    float wwn = scal[2] * (scal[1] * alloc_t + (1.f - scal[1]) * cwv);
    ws[OFF_WW + t] = wwn;

    float nn2 = 0.f;
    #pragma unroll
    for (int w = 0; w < 32; ++w) {
        float mn = mrow[w] * (1.f - wwn * er[w]) + wwn * wvv[w];
        mrow[w] = mn; nn2 += mn * mn;
        ws[OFF_MEMNEW + t * 32 + w] = mn;
    }
    float inv2 = 1.f / fmaxf(sqrtf(nn2), EPSV);

    if (t < 8) {
        float s3 = 0.f;
        #pragma unroll
        for (int w = 0; w < 32; ++w) { float x = rk[w * 8 + t]; s3 += x * x; }
        srk[t] = rss[t] / fmaxf(sqrtf(s3), EPSV);
    }
    __syncthreads();

    float sc[8];
    #pragma unroll
    for (int r = 0; r < 8; ++r) {
        float d2 = 0.f;
        #pragma unroll
        for (int w = 0; w < 32; ++w) d2 += mrow[w] * rk[w * 8 + r];
        sc[r] = srk[r] * inv2 * d2;
    }
    #pragma unroll
    for (int r = 0; r < 8; ++r) {
        float x = sc[r];
        #pragma unroll
        for (int o = 32; o > 0; o >>= 1) x = fmaxf(x, __shfl_xor(x, o));
        if (lane == 0) wred8[wid * 8 + r] = x;
    }
    __syncthreads();
    float mxr[8];
    #pragma unroll
    for (int r = 0; r < 8; ++r) {
        float m = wred8[r];
        #pragma unroll
        for (int qq = 1; qq < 8; ++qq) m = fmaxf(m, wred8[qq * 8 + r]);
        mxr[r] = m;
    }
    __syncthreads();
    float ex[8];
    #pragma unroll
    for (int r = 0; r < 8; ++r) {
        ex[r] = expf(sc[r] - mxr[r]);
        float x = ex[r];
        #pragma unroll
        for (int o = 32; o > 0; o >>= 1) x += __shfl_xor(x, o);
        if (lane == 0) wred8[wid * 8 + r] = x;
    }
    __syncthreads();
    #pragma unroll
    for (int r = 0; r < 8; ++r) {
        float sm = 0.f;
        #pragma unroll
        for (int qq = 0; qq < 8; ++qq) sm += wred8[qq * 8 + r];
        ws[OFF_CR + t * 8 + r] = ex[r] / sm;
    }
    if (t < 24) ws[OFF_RM + t] = rm[t];
}

// ---- K7: linkage fw/bw (2 rows each per block) + rv partial atomics -------
__global__ __launch_bounds__(512) void k7_linkage(
    const float* __restrict__ linkage, const float* __restrict__ prec,
    const float* __restrict__ lrw, float* __restrict__ ws)
{
    const int blk = blockIdx.x, t = threadIdx.x;
    const int lane = t & 63, wid = t >> 6;
    __shared__ float lrw_s[4608];    // 512*9 padded
    __shared__ float ww_s[512];
    __shared__ float rowred[64];
    __shared__ float fwbw_s[2][2][8];   // [fw=0/bw=1][row-in-pair][r]

    for (int i = t; i < 4096; i += 512)
        lrw_s[(i >> 3) * 9 + (i & 7)] = lrw[i];
    ww_s[t] = ws[OFF_WW + t];
    __syncthreads();

    const float pt = prec[t];
    const float wwt = ww_s[t];
    float la[8];
    #pragma unroll
    for (int r = 0; r < 8; ++r) la[r] = lrw_s[t * 9 + r];

    #pragma unroll
    for (int pass = 0; pass < 4; ++pass) {
        const int i = blk * 2 + (pass & 1);
        float lm;
        if (pass < 2) {   // fw: Lm[i][t]
            float lj = linkage[(size_t)i * 512 + t];
            lm = (t == i) ? 0.f : (1.f - ww_s[i] - wwt) * lj + ww_s[i] * pt;
        } else {          // bw: Lm[t][i]
            float lj = linkage[(size_t)t * 512 + i];
            lm = (t == i) ? 0.f : (1.f - wwt - ww_s[i]) * lj + wwt * prec[i];
        }
        #pragma unroll
        for (int r = 0; r < 8; ++r) {
            float v = lm * la[r];
            #pragma unroll
            for (int o = 32; o > 0; o >>= 1) v += __shfl_xor(v, o);
            if (lane == 0) rowred[wid * 8 + r] = v;
        }
        __syncthreads();
        if (t < 8) {
            float s = 0.f;
            #pragma unroll
            for (int w = 0; w < 8; ++w) s += rowred[w * 8 + t];
            ws[((pass < 2) ? OFF_FW : OFF_BW) + i * 8 + t] = s;
            fwbw_s[pass >> 1][pass & 1][t] = s;
        }
        __syncthreads();
    }

    // rv partial: this block owns rows n = 2*blk, 2*blk+1
    if (t < 256) {
        const int w = t >> 3, r = t & 7;
        const float rm0 = ws[OFF_RM + r * 3];
        const float rm1 = ws[OFF_RM + r * 3 + 1];
        const float rm2 = ws[OFF_RM + r * 3 + 2];
        float val = 0.f;
        #pragma unroll
        for (int p2 = 0; p2 < 2; ++p2) {
            int n = blk * 2 + p2;
            float rwn = fwbw_s[1][p2][r] * rm0
                      + ws[OFF_CR + n * 8 + r] * rm1
                      + fwbw_s[0][p2][r] * rm2;
            val += ws[OFF_MEMNEW + n * 32 + w] * rwn;
        }
        atomicAdd(&ws[OFF_RV + t], val);
    }
}

// ---- KOUT: out = flat@Wy + rv@Wr (227 blocks, direct store) ---------------
__global__ __launch_bounds__(512) void kout(
    const float* __restrict__ Wy, const float* __restrict__ Wr,
    float* __restrict__ dout, const float* __restrict__ ws)
{
    const int blk = blockIdx.x, t = threadIdx.x;
    __shared__ float flat_s[1024];
    __shared__ float rv_s[256];
    __shared__ float pr[512];
    flat_s[t]       = ws[OFF_FLAT + t];
    flat_s[512 + t] = ws[OFF_FLAT + 512 + t];
    if (t < 256) rv_s[t] = ws[OFF_RV + t];
    __syncthreads();

    const int ks = t >> 4, v16 = t & 15;     // 32 k-segs
    const int v = blk * 16 + v16;
    float acc = 0.f;
    if (v < VTDIM) {
        const float* Wp = Wy + (size_t)(ks * 32) * VTDIM + v;
        #pragma unroll 8
        for (int k = 0; k < 32; ++k)
            acc += flat_s[ks * 32 + k] * Wp[(size_t)k * VTDIM];
        const float* Wp2 = Wr + (size_t)(ks * 8) * VTDIM + v;
        #pragma unroll
        for (int k = 0; k < 8; ++k)
            acc += rv_s[ks * 8 + k] * Wp2[(size_t)k * VTDIM];
    }
    pr[ks * 16 + v16] = acc;
    __syncthreads();
    if (t < 16) {
        int vv = blk * 16 + t;
        if (vv < VTDIM) {
            float s = 0.f;
            #pragma unroll
            for (int q = 0; q < 32; ++q) s += pr[q * 16 + t];
            dout[vv] = s;
        }
    }
}

extern "C" void kernel_launch(void* const* d_in, const int* in_sizes, int n_in,
                              void* d_out, int out_size, void* d_ws, size_t ws_size,
                              hipStream_t stream)
{
    const float* x_in   = (const float*)d_in[0];
    const float* Wi     = (const float*)d_in[1];
    const float* bi     = (const float*)d_in[2];
    const float* Wf     = (const float*)d_in[3];
    const float* bf     = (const float*)d_in[4];
    const float* Wo     = (const float*)d_in[5];
    const float* bo     = (const float*)d_in[6];
    const float* Wss    = (const float*)d_in[7];
    const float* bs     = (const float*)d_in[8];
    const float* Wy     = (const float*)d_in[9];
    const float* We     = (const float*)d_in[10];
    const float* Wr     = (const float*)d_in[11];
    const float* memory = (const float*)d_in[12];
    const float* lrv    = (const float*)d_in[13];
    const float* hprev  = (const float*)d_in[14];
    const float* old_st = (const float*)d_in[15];
    const float* prec   = (const float*)d_in[16];
    const float* linkage= (const float*)d_in[17];
    const float* lrw    = (const float*)d_in[18];
    const float* lu     = (const float*)d_in[19];
    const float* lww    = (const float*)d_in[20];
    float* out = (float*)d_out;
    float* ws  = (float*)d_ws;

    // zero fixed-gate accumulators (4096 floats) + election counter
    hipMemsetAsync((void*)ws, 0, (4096 + 4) * sizeof(float), stream);

    k1_partial<<<K1_COMPUTE + K1_COPYB, 256, 0, stream>>>(
        x_in, lrv, hprev, Wi, Wf, Wo, Wss, ws);
    k3_recurrent<<<1, 1024, 0, stream>>>(bi, bf, bo, bs, old_st, ws);
    kE6<<<KE_BLOCKS, 512, 0, stream>>>(We, memory, lrw, lu, lww, ws);
    k7_linkage<<<256, 512, 0, stream>>>(linkage, prec, lrw, ws);
    kout<<<227, 512, 0, stream>>>(Wy, Wr, out, ws);
}